// Round 1
// baseline (882.587 us; speedup 1.0000x reference)
//
#include <hip/hip_runtime.h>
#include <hip/hip_bf16.h>
#include <math.h>

#define NN 20000
#define EE 320000
#define ETOT (EE + NN)   // 340000
#define BB 64
#define FIN 128
#define HH 512
#define OUTC 10

// ---------------- GEMM: C[M,512] = A[M,K] @ W[K,512], f32 ----------------
template<int K>
__global__ __launch_bounds__(256) void k_gemm(const float* __restrict__ A,
                                              const float* __restrict__ Wm,
                                              float* __restrict__ C, int M) {
    constexpr int BM = 64, BN = 64, BK = 16;
    __shared__ float As[BK][BM + 1];
    __shared__ float Bs[BK][BN];
    const int tid  = threadIdx.x;
    const int row0 = blockIdx.y * BM;
    const int col0 = blockIdx.x * BN;
    const int tr = (tid >> 4) << 2;   // 0..60 step 4
    const int tc = (tid & 15) << 2;   // 0..60 step 4
    float acc[4][4] = {};
    for (int k0 = 0; k0 < K; k0 += BK) {
        #pragma unroll
        for (int i = 0; i < 4; ++i) {
            int idx = tid + i * 256;          // 0..1023
            int r = idx >> 4, c = idx & 15;   // A tile 64x16
            int gr = row0 + r;
            As[c][r] = (gr < M) ? A[(size_t)gr * K + k0 + c] : 0.f;
            int br = idx >> 6, bc = idx & 63; // B tile 16x64
            Bs[br][bc] = Wm[(size_t)(k0 + br) * HH + col0 + bc];
        }
        __syncthreads();
        #pragma unroll
        for (int kk = 0; kk < BK; ++kk) {
            float a[4], b[4];
            #pragma unroll
            for (int i = 0; i < 4; ++i) a[i] = As[kk][tr + i];
            #pragma unroll
            for (int j = 0; j < 4; ++j) b[j] = Bs[kk][tc + j];
            #pragma unroll
            for (int i = 0; i < 4; ++i)
                #pragma unroll
                for (int j = 0; j < 4; ++j)
                    acc[i][j] += a[i] * b[j];
        }
        __syncthreads();
    }
    #pragma unroll
    for (int i = 0; i < 4; ++i) {
        int gr = row0 + tr + i;
        if (gr < M) {
            #pragma unroll
            for (int j = 0; j < 4; ++j)
                C[(size_t)gr * HH + col0 + tc + j] = acc[i][j];
        }
    }
}

// ---------------- attention scores es/ed: one wave per row ----------------
__global__ __launch_bounds__(256) void k_scores(const float* __restrict__ h,
                                                const float* __restrict__ a_s,
                                                const float* __restrict__ a_d,
                                                float* __restrict__ es,
                                                float* __restrict__ ed) {
    int wid  = threadIdx.x >> 6;
    int lane = threadIdx.x & 63;
    int row  = blockIdx.x * 4 + wid;
    if (row >= NN) return;
    const float4* hr = (const float4*)(h + (size_t)row * HH);
    const float4* as4 = (const float4*)a_s;
    const float4* ad4 = (const float4*)a_d;
    float s = 0.f, d = 0.f;
    #pragma unroll
    for (int i = 0; i < 2; ++i) {
        float4 hv = hr[2 * lane + i];
        float4 av = as4[2 * lane + i];
        float4 dv = ad4[2 * lane + i];
        s += hv.x * av.x + hv.y * av.y + hv.z * av.z + hv.w * av.w;
        d += hv.x * dv.x + hv.y * dv.y + hv.z * dv.z + hv.w * dv.w;
    }
    #pragma unroll
    for (int o = 32; o > 0; o >>= 1) {
        s += __shfl_down(s, o);
        d += __shfl_down(d, o);
    }
    if (lane == 0) { es[row] = s; ed[row] = d; }
}

// ---------------- CSR build ----------------
__global__ void k_deg(const int* __restrict__ eidx, int* __restrict__ deg) {
    int e = blockIdx.x * 256 + threadIdx.x;
    if (e >= ETOT) return;
    int d = (e < EE) ? eidx[EE + e] : (e - EE);
    atomicAdd(&deg[d], 1);
}

__global__ __launch_bounds__(1024) void k_scan(const int* __restrict__ deg,
                                               int* __restrict__ offs) {
    __shared__ int buf[1024];
    __shared__ int base;
    int t = threadIdx.x;
    if (t == 0) base = 0;
    __syncthreads();
    for (int start = 0; start < NN; start += 1024) {
        int i = start + t;
        int v = (i < NN) ? deg[i] : 0;
        buf[t] = v;
        __syncthreads();
        for (int off = 1; off < 1024; off <<= 1) {
            int add = (t >= off) ? buf[t - off] : 0;
            __syncthreads();
            buf[t] += add;
            __syncthreads();
        }
        if (i < NN) offs[i] = base + buf[t] - v;
        __syncthreads();
        if (t == 0) base += buf[1023];
        __syncthreads();
    }
    if (t == 0) offs[NN] = base;
}

__global__ void k_fill(const int* __restrict__ eidx, const int* __restrict__ offs,
                       int* __restrict__ cursor, int* __restrict__ csr) {
    int e = blockIdx.x * 256 + threadIdx.x;
    if (e >= ETOT) return;
    int s, d;
    if (e < EE) { s = eidx[e]; d = eidx[EE + e]; }
    else        { s = e - EE;  d = e - EE; }
    int pos = offs[d] + atomicAdd(&cursor[d], 1);
    csr[pos] = s;
}

// ---------------- per-dst softmax-weighted aggregation ----------------
__global__ __launch_bounds__(256) void k_agg(const float* __restrict__ h,
                                             const float* __restrict__ es,
                                             const float* __restrict__ ed,
                                             const int* __restrict__ offs,
                                             const int* __restrict__ csr,
                                             const float* __restrict__ bias,
                                             float* __restrict__ out) {
    __shared__ float red[4];
    __shared__ float bcast;
    int dnode = blockIdx.x;
    int beg = offs[dnode], end = offs[dnode + 1];
    float edv = ed[dnode];
    int tid = threadIdx.x;
    int lane = tid & 63, wid = tid >> 6;

    // pass 1: max of leaky_relu(es[src]+edv)
    float lmax = -1e30f;
    for (int i = beg + tid; i < end; i += 256) {
        float v = es[csr[i]] + edv;
        v = v > 0.f ? v : 0.2f * v;
        lmax = fmaxf(lmax, v);
    }
    #pragma unroll
    for (int o = 32; o > 0; o >>= 1) lmax = fmaxf(lmax, __shfl_down(lmax, o));
    if (lane == 0) red[wid] = lmax;
    __syncthreads();
    if (tid == 0)
        bcast = fmaxf(fmaxf(red[0], red[1]), fmaxf(red[2], red[3]));
    __syncthreads();
    float m = bcast;
    __syncthreads();

    // pass 2: z = sum exp(e - m)
    float lz = 0.f;
    for (int i = beg + tid; i < end; i += 256) {
        float v = es[csr[i]] + edv;
        v = v > 0.f ? v : 0.2f * v;
        lz += expf(v - m);
    }
    #pragma unroll
    for (int o = 32; o > 0; o >>= 1) lz += __shfl_down(lz, o);
    if (lane == 0) red[wid] = lz;
    __syncthreads();
    if (tid == 0) bcast = red[0] + red[1] + red[2] + red[3];
    __syncthreads();
    float inv = 1.f / (bcast + 1e-16f);

    // pass 3: out[d,f] = sum_i alpha_i * h[src_i, f]
    int f0 = tid, f1 = tid + 256;
    float a0 = 0.f, a1 = 0.f;
    for (int i = beg; i < end; ++i) {
        int s = csr[i];
        float v = es[s] + edv;
        v = v > 0.f ? v : 0.2f * v;
        float w = expf(v - m) * inv;
        a0 += w * h[(size_t)s * HH + f0];
        a1 += w * h[(size_t)s * HH + f1];
    }
    out[(size_t)dnode * HH + f0] = a0 + bias[f0];
    out[(size_t)dnode * HH + f1] = a1 + bias[f1];
}

// ---------------- BatchNorm stats / apply ----------------
__global__ __launch_bounds__(256) void k_bnstats(const float* __restrict__ X,
                                                 float* __restrict__ sum,
                                                 float* __restrict__ sumsq) {
    int f0 = threadIdx.x, f1 = threadIdx.x + 256;
    int rows_per = (NN + gridDim.x - 1) / gridDim.x;
    int r0 = blockIdx.x * rows_per;
    int r1 = min(NN, r0 + rows_per);
    float s0 = 0, s1 = 0, q0 = 0, q1 = 0;
    for (int r = r0; r < r1; ++r) {
        float v0 = X[(size_t)r * HH + f0];
        float v1 = X[(size_t)r * HH + f1];
        s0 += v0; q0 += v0 * v0;
        s1 += v1; q1 += v1 * v1;
    }
    atomicAdd(&sum[f0], s0);   atomicAdd(&sum[f1], s1);
    atomicAdd(&sumsq[f0], q0); atomicAdd(&sumsq[f1], q1);
}

__global__ void k_bnapply(float* __restrict__ X, const float* __restrict__ sum,
                          const float* __restrict__ sumsq,
                          const float* __restrict__ g, const float* __restrict__ be) {
    const float invN = 1.f / (float)NN;
    size_t stride = (size_t)gridDim.x * 256;
    for (size_t i = (size_t)blockIdx.x * 256 + threadIdx.x; i < (size_t)NN * HH; i += stride) {
        int f = (int)(i & (HH - 1));
        float mu = sum[f] * invN;
        float var = sumsq[f] * invN - mu * mu;
        float v = (X[i] - mu) * rsqrtf(var + 1e-5f) * g[f] + be[f];
        X[i] = v > 0.f ? v : 0.f;
    }
}

// ---------------- mean pool per graph ----------------
__device__ __forceinline__ int lb_search(const int* __restrict__ batch, int val) {
    int lo = 0, hi = NN;
    while (lo < hi) { int mid = (lo + hi) >> 1; if (batch[mid] < val) lo = mid + 1; else hi = mid; }
    return lo;
}

__global__ __launch_bounds__(256) void k_pool(const float* __restrict__ X,
                                              const int* __restrict__ batch,
                                              float* __restrict__ P) {
    int b = blockIdx.x;
    int lo = lb_search(batch, b), hi = lb_search(batch, b + 1);
    int f0 = threadIdx.x, f1 = threadIdx.x + 256;
    float s0 = 0.f, s1 = 0.f;
    for (int r = lo; r < hi; ++r) {
        s0 += X[(size_t)r * HH + f0];
        s1 += X[(size_t)r * HH + f1];
    }
    float inv = 1.f / fmaxf((float)(hi - lo), 1.f);
    P[b * HH + f0] = s0 * inv;
    P[b * HH + f1] = s1 * inv;
}

// ---------------- final FC head + log_softmax ----------------
__global__ __launch_bounds__(256) void k_head(const float* __restrict__ x1,
                                              const float* __restrict__ x2,
                                              const float* __restrict__ fcW,
                                              const float* __restrict__ fcb,
                                              const float* __restrict__ f1W,
                                              const float* __restrict__ f1b,
                                              float* __restrict__ out) {
    __shared__ float zrow[512];
    __shared__ float hid[256];
    __shared__ float o[16];
    int b = blockIdx.x, t = threadIdx.x;
    zrow[t]       = x1[b * HH + t]       + x2[b * HH + t];
    zrow[t + 256] = x1[b * HH + t + 256] + x2[b * HH + t + 256];
    __syncthreads();
    float acc = fcb[t];
    for (int k = 0; k < 512; ++k) acc += zrow[k] * fcW[k * 256 + t];
    hid[t] = fmaxf(acc, 0.f);
    __syncthreads();
    if (t < OUTC) {
        float a = f1b[t];
        for (int k = 0; k < 256; ++k) a += hid[k] * f1W[k * OUTC + t];
        o[t] = a;
    }
    __syncthreads();
    if (t == 0) {
        float mx = -1e30f;
        for (int j = 0; j < OUTC; ++j) mx = fmaxf(mx, o[j]);
        float s = 0.f;
        for (int j = 0; j < OUTC; ++j) s += expf(o[j] - mx);
        float lse = mx + logf(s);
        for (int j = 0; j < OUTC; ++j) out[b * OUTC + j] = o[j] - lse;
    }
}

// ---------------- launch ----------------
extern "C" void kernel_launch(void* const* d_in, const int* in_sizes, int n_in,
                              void* d_out, int out_size, void* d_ws, size_t ws_size,
                              hipStream_t stream) {
    const float* x      = (const float*)d_in[0];
    const int*   eidx   = (const int*)  d_in[1];
    const int*   batch  = (const int*)  d_in[2];
    const float* W1     = (const float*)d_in[3];
    const float* a_src1 = (const float*)d_in[4];
    const float* a_dst1 = (const float*)d_in[5];
    const float* b1     = (const float*)d_in[6];
    const float* g1     = (const float*)d_in[7];
    const float* be1    = (const float*)d_in[8];
    const float* W2     = (const float*)d_in[9];
    const float* a_src2 = (const float*)d_in[10];
    const float* a_dst2 = (const float*)d_in[11];
    const float* b2     = (const float*)d_in[12];
    const float* g2     = (const float*)d_in[13];
    const float* be2    = (const float*)d_in[14];
    const float* fcW    = (const float*)d_in[15];
    const float* fcb    = (const float*)d_in[16];
    const float* fc1W   = (const float*)d_in[17];
    const float* fc1b   = (const float*)d_in[18];
    float* out = (float*)d_out;

    // workspace carve-up
    float* bufA   = (float*)d_ws;                 // N*H
    float* bufB   = bufA + (size_t)NN * HH;       // N*H
    float* es     = bufB + (size_t)NN * HH;       // N
    float* ed     = es + NN;                      // N
    float* bnsum1 = ed + NN;                      // H
    float* bnsq1  = bnsum1 + HH;                  // H
    float* bnsum2 = bnsq1 + HH;                   // H
    float* bnsq2  = bnsum2 + HH;                  // H
    float* x1     = bnsq2 + HH;                   // B*H
    float* x2     = x1 + BB * HH;                 // B*H
    int*   deg    = (int*)(x2 + BB * HH);         // N
    int*   offs   = deg + NN;                     // N+1
    int*   cursor = offs + NN + 1;                // N
    int*   csr    = cursor + NN;                  // ETOT

    // zero accumulators
    hipMemsetAsync(bnsum1, 0, 4 * HH * sizeof(float), stream);  // covers bnsum1..bnsq2
    hipMemsetAsync(deg, 0, NN * sizeof(int), stream);
    hipMemsetAsync(cursor, 0, NN * sizeof(int), stream);

    // CSR build (shared by both layers)
    int eblocks = (ETOT + 255) / 256;
    k_deg<<<eblocks, 256, 0, stream>>>(eidx, deg);
    k_scan<<<1, 1024, 0, stream>>>(deg, offs);
    k_fill<<<eblocks, 256, 0, stream>>>(eidx, offs, cursor, csr);

    dim3 gemmGrid(HH / 64, (NN + 63) / 64);

    // ---- layer 1 ----
    k_gemm<FIN><<<gemmGrid, 256, 0, stream>>>(x, W1, bufA, NN);
    k_scores<<<(NN + 3) / 4, 256, 0, stream>>>(bufA, a_src1, a_dst1, es, ed);
    k_agg<<<NN, 256, 0, stream>>>(bufA, es, ed, offs, csr, b1, bufB);
    k_bnstats<<<80, 256, 0, stream>>>(bufB, bnsum1, bnsq1);
    k_bnapply<<<2048, 256, 0, stream>>>(bufB, bnsum1, bnsq1, g1, be1);
    k_pool<<<BB, 256, 0, stream>>>(bufB, batch, x1);

    // ---- layer 2 ----
    k_gemm<HH><<<gemmGrid, 256, 0, stream>>>(bufB, W2, bufA, NN);
    k_scores<<<(NN + 3) / 4, 256, 0, stream>>>(bufA, a_src2, a_dst2, es, ed);
    k_agg<<<NN, 256, 0, stream>>>(bufA, es, ed, offs, csr, b2, bufB);
    k_bnstats<<<80, 256, 0, stream>>>(bufB, bnsum2, bnsq2);
    k_bnapply<<<2048, 256, 0, stream>>>(bufB, bnsum2, bnsq2, g2, be2);
    k_pool<<<BB, 256, 0, stream>>>(bufB, batch, x2);

    // ---- head ----
    k_head<<<BB, 256, 0, stream>>>(x1, x2, fcW, fcb, fc1W, fc1b, out);
}

// Round 2
// 523.676 us; speedup vs baseline: 1.6854x; 1.6854x over previous
//
#include <hip/hip_runtime.h>
#include <hip/hip_bf16.h>
#include <math.h>

#define NN 20000
#define EE 320000
#define ETOT (EE + NN)   // 340000
#define BB 64
#define FIN 128
#define HH 512
#define OUTC 10

typedef __attribute__((ext_vector_type(8))) short short8;
typedef __attribute__((ext_vector_type(4))) float f32x4;

__device__ __forceinline__ unsigned short f2bf(float f) {
    unsigned int u = __float_as_uint(f);
    u += 0x7FFFu + ((u >> 16) & 1u);
    return (unsigned short)(u >> 16);
}
__device__ __forceinline__ float bf2f_lo(unsigned int u) { return __uint_as_float(u << 16); }
__device__ __forceinline__ float bf2f_hi(unsigned int u) { return __uint_as_float(u & 0xFFFF0000u); }

// ---------------- cast x -> bf16 ----------------
__global__ __launch_bounds__(256) void k_cast(const float* __restrict__ x,
                                              unsigned short* __restrict__ x16, int n4) {
    int i = blockIdx.x * 256 + threadIdx.x;
    if (i >= n4) return;
    float4 v = ((const float4*)x)[i];
    unsigned short o[4] = { f2bf(v.x), f2bf(v.y), f2bf(v.z), f2bf(v.w) };
    *(ushort4*)(x16 + 4 * (size_t)i) = *(const ushort4*)o;
}

// ---------------- W [K][512] f32 -> WT [512][K] bf16 ----------------
template<int K>
__global__ __launch_bounds__(256) void k_wt(const float* __restrict__ W,
                                            unsigned short* __restrict__ WT) {
    int idx = blockIdx.x * 256 + threadIdx.x;
    if (idx >= 512 * K) return;
    int n = idx / K, k = idx % K;
    WT[idx] = f2bf(W[k * 512 + n]);
}

// ---------------- bf16 MFMA GEMM: C16[M,512] = A16[M,K] @ (BT16[512,K])^T ----
template<int K>
__global__ __launch_bounds__(256) void k_gemm16(const unsigned short* __restrict__ A,
                                                const unsigned short* __restrict__ BT,
                                                unsigned short* __restrict__ C,
                                                int M) {
    __shared__ __align__(16) short As[128][72];   // +8 pad: 144B row stride -> conflict-free frags
    __shared__ __align__(16) short Bs[128][72];
    const int tid  = threadIdx.x;
    const int lane = tid & 63;
    const int wid  = tid >> 6;
    const int wr = wid >> 1, wc = wid & 1;        // 2x2 wave grid, 64x64 per wave
    const int row0 = blockIdx.y * 128, col0 = blockIdx.x * 128;
    f32x4 acc[4][4] = {};
    for (int k0 = 0; k0 < K; k0 += 64) {
        #pragma unroll
        for (int i = 0; i < 4; ++i) {
            int cid = tid + i * 256;              // 1024 chunks of 8 bf16
            int r = cid >> 3, c = cid & 7;
            int ga = min(row0 + r, M - 1);
            uint4 av = *(const uint4*)(A  + (size_t)ga * K + k0 + c * 8);
            *(uint4*)&As[r][c * 8] = av;
            uint4 bv = *(const uint4*)(BT + (size_t)(col0 + r) * K + k0 + c * 8);
            *(uint4*)&Bs[r][c * 8] = bv;
        }
        __syncthreads();
        #pragma unroll
        for (int kk = 0; kk < 64; kk += 32) {
            short8 af[4], bf[4];
            const int koff = kk + (lane >> 4) * 8;
            const int ar = wr * 64 + (lane & 15);
            const int br = wc * 64 + (lane & 15);
            #pragma unroll
            for (int m = 0; m < 4; ++m) af[m] = *(const short8*)&As[ar + m * 16][koff];
            #pragma unroll
            for (int n = 0; n < 4; ++n) bf[n] = *(const short8*)&Bs[br + n * 16][koff];
            #pragma unroll
            for (int m = 0; m < 4; ++m)
                #pragma unroll
                for (int n = 0; n < 4; ++n)
                    acc[m][n] = __builtin_amdgcn_mfma_f32_16x16x32_bf16(af[m], bf[n], acc[m][n], 0, 0, 0);
        }
        __syncthreads();
    }
    const int crow = (lane >> 4) * 4;
    const int ccol = lane & 15;
    #pragma unroll
    for (int m = 0; m < 4; ++m) {
        #pragma unroll
        for (int j = 0; j < 4; ++j) {
            int gr = row0 + wr * 64 + m * 16 + crow + j;
            if (gr < M) {
                #pragma unroll
                for (int n = 0; n < 4; ++n)
                    C[(size_t)gr * 512 + col0 + wc * 64 + n * 16 + ccol] = f2bf(acc[m][n][j]);
            }
        }
    }
}

// ---------------- attention scores from bf16 h: one wave per row ----------------
__global__ __launch_bounds__(256) void k_scores16(const unsigned short* __restrict__ h16,
                                                  const float* __restrict__ a_s,
                                                  const float* __restrict__ a_d,
                                                  float* __restrict__ es,
                                                  float* __restrict__ ed) {
    int wid  = threadIdx.x >> 6;
    int lane = threadIdx.x & 63;
    int row  = blockIdx.x * 4 + wid;
    if (row >= NN) return;
    uint4 hv = *(const uint4*)(h16 + (size_t)row * 512 + lane * 8);
    const float4* as4 = (const float4*)a_s;
    const float4* ad4 = (const float4*)a_d;
    float4 a0 = as4[2 * lane], a1 = as4[2 * lane + 1];
    float4 d0 = ad4[2 * lane], d1 = ad4[2 * lane + 1];
    float h0 = bf2f_lo(hv.x), h1 = bf2f_hi(hv.x), h2 = bf2f_lo(hv.y), h3 = bf2f_hi(hv.y);
    float h4 = bf2f_lo(hv.z), h5 = bf2f_hi(hv.z), h6 = bf2f_lo(hv.w), h7 = bf2f_hi(hv.w);
    float s = h0*a0.x + h1*a0.y + h2*a0.z + h3*a0.w + h4*a1.x + h5*a1.y + h6*a1.z + h7*a1.w;
    float d = h0*d0.x + h1*d0.y + h2*d0.z + h3*d0.w + h4*d1.x + h5*d1.y + h6*d1.z + h7*d1.w;
    #pragma unroll
    for (int o = 32; o > 0; o >>= 1) {
        s += __shfl_down(s, o);
        d += __shfl_down(d, o);
    }
    if (lane == 0) { es[row] = s; ed[row] = d; }
}

// ---------------- CSR build ----------------
__global__ void k_deg(const int* __restrict__ eidx, int* __restrict__ deg) {
    int e = blockIdx.x * 256 + threadIdx.x;
    if (e >= ETOT) return;
    int d = (e < EE) ? eidx[EE + e] : (e - EE);
    atomicAdd(&deg[d], 1);
}

__global__ __launch_bounds__(1024) void k_scan(const int* __restrict__ deg,
                                               int* __restrict__ offs) {
    __shared__ int partials[1024];
    int t = threadIdx.x;
    const int per = (NN + 1023) / 1024;   // 20
    int b0 = t * per;
    int s = 0;
    for (int i = 0; i < per; ++i) { int idx = b0 + i; if (idx < NN) s += deg[idx]; }
    partials[t] = s;
    __syncthreads();
    for (int off = 1; off < 1024; off <<= 1) {
        int v = (t >= off) ? partials[t - off] : 0;
        __syncthreads();
        partials[t] += v;
        __syncthreads();
    }
    int base = (t == 0) ? 0 : partials[t - 1];
    for (int i = 0; i < per; ++i) {
        int idx = b0 + i;
        if (idx < NN) { offs[idx] = base; base += deg[idx]; }
    }
    if (t == 1023) offs[NN] = partials[1023];
}

__global__ void k_fill(const int* __restrict__ eidx, const int* __restrict__ offs,
                       int* __restrict__ cursor, int* __restrict__ csr) {
    int e = blockIdx.x * 256 + threadIdx.x;
    if (e >= ETOT) return;
    int s, d;
    if (e < EE) { s = eidx[e]; d = eidx[EE + e]; }
    else        { s = e - EE;  d = e - EE; }
    int pos = offs[d] + atomicAdd(&cursor[d], 1);
    csr[pos] = s;
}

// ---------------- per-dst softmax-weighted aggregation (bf16 gathers) ----------------
__global__ __launch_bounds__(256) void k_agg(const unsigned short* __restrict__ h16,
                                             const float* __restrict__ es,
                                             const float* __restrict__ ed,
                                             const int* __restrict__ offs,
                                             const int* __restrict__ csr,
                                             const float* __restrict__ bias,
                                             float* __restrict__ out) {
    __shared__ float red[4];
    __shared__ float bcast;
    __shared__ float sh_w[256];
    __shared__ int   sh_s[256];
    int dnode = blockIdx.x;
    int beg = offs[dnode], end = offs[dnode + 1];
    float edv = ed[dnode];
    int tid = threadIdx.x;
    int lane = tid & 63, w4 = tid >> 6;

    // pass 1: z = sum exp(leaky_relu(es+ed))   (no max shift: |e| <~ 10 << 88)
    float lz = 0.f;
    for (int i = beg + tid; i < end; i += 256) {
        float v = es[csr[i]] + edv;
        v = v > 0.f ? v : 0.2f * v;
        lz += __expf(v);
    }
    #pragma unroll
    for (int o = 32; o > 0; o >>= 1) lz += __shfl_down(lz, o);
    if (lane == 0) red[w4] = lz;
    __syncthreads();
    if (tid == 0) bcast = red[0] + red[1] + red[2] + red[3];
    __syncthreads();
    float inv = 1.f / (bcast + 1e-16f);

    // pass 2: chunked: per-edge weight computed once into LDS, then coalesced row gathers
    float a0 = 0.f, a1 = 0.f;
    const int f = tid * 2;
    for (int c0 = beg; c0 < end; c0 += 256) {
        int nc = min(256, end - c0);
        __syncthreads();
        if (tid < nc) {
            int s = csr[c0 + tid];
            float v = es[s] + edv;
            v = v > 0.f ? v : 0.2f * v;
            sh_w[tid] = __expf(v) * inv;
            sh_s[tid] = s;
        }
        __syncthreads();
        for (int j = 0; j < nc; ++j) {
            int s = sh_s[j];
            float w = sh_w[j];
            unsigned int u = *(const unsigned int*)(h16 + (size_t)s * 512 + f);
            a0 += w * bf2f_lo(u);
            a1 += w * bf2f_hi(u);
        }
    }
    out[(size_t)dnode * 512 + f]     = a0 + bias[f];
    out[(size_t)dnode * 512 + f + 1] = a1 + bias[f + 1];
}

// ---------------- BatchNorm stats / apply ----------------
__global__ __launch_bounds__(256) void k_bnstats(const float* __restrict__ X,
                                                 float* __restrict__ sum,
                                                 float* __restrict__ sumsq) {
    int f0 = threadIdx.x, f1 = threadIdx.x + 256;
    int rows_per = (NN + gridDim.x - 1) / gridDim.x;
    int r0 = blockIdx.x * rows_per;
    int r1 = min(NN, r0 + rows_per);
    float s0 = 0, s1 = 0, q0 = 0, q1 = 0;
    for (int r = r0; r < r1; ++r) {
        float v0 = X[(size_t)r * HH + f0];
        float v1 = X[(size_t)r * HH + f1];
        s0 += v0; q0 += v0 * v0;
        s1 += v1; q1 += v1 * v1;
    }
    atomicAdd(&sum[f0], s0);   atomicAdd(&sum[f1], s1);
    atomicAdd(&sumsq[f0], q0); atomicAdd(&sumsq[f1], q1);
}

// BN + ReLU, writes f32 (for pool) and bf16 (for next GEMM)
__global__ void k_bnapply(float* __restrict__ X, unsigned short* __restrict__ X16,
                          const float* __restrict__ sum, const float* __restrict__ sumsq,
                          const float* __restrict__ g, const float* __restrict__ be) {
    const float invN = 1.f / (float)NN;
    size_t stride = (size_t)gridDim.x * 256;
    for (size_t i = (size_t)blockIdx.x * 256 + threadIdx.x; i < (size_t)NN * HH; i += stride) {
        int f = (int)(i & (HH - 1));
        float mu = sum[f] * invN;
        float var = sumsq[f] * invN - mu * mu;
        float v = (X[i] - mu) * rsqrtf(var + 1e-5f) * g[f] + be[f];
        v = v > 0.f ? v : 0.f;
        X[i] = v;
        X16[i] = f2bf(v);
    }
}

// ---------------- mean pool per graph ----------------
__device__ __forceinline__ int lb_search(const int* __restrict__ batch, int val) {
    int lo = 0, hi = NN;
    while (lo < hi) { int mid = (lo + hi) >> 1; if (batch[mid] < val) lo = mid + 1; else hi = mid; }
    return lo;
}

__global__ __launch_bounds__(256) void k_pool(const float* __restrict__ X,
                                              const int* __restrict__ batch,
                                              float* __restrict__ P) {
    int b = blockIdx.x;
    int lo = lb_search(batch, b), hi = lb_search(batch, b + 1);
    int f0 = threadIdx.x, f1 = threadIdx.x + 256;
    float s0 = 0.f, s1 = 0.f;
    for (int r = lo; r < hi; ++r) {
        s0 += X[(size_t)r * HH + f0];
        s1 += X[(size_t)r * HH + f1];
    }
    float inv = 1.f / fmaxf((float)(hi - lo), 1.f);
    P[b * HH + f0] = s0 * inv;
    P[b * HH + f1] = s1 * inv;
}

// ---------------- final FC head + log_softmax ----------------
__global__ __launch_bounds__(256) void k_head(const float* __restrict__ x1,
                                              const float* __restrict__ x2,
                                              const float* __restrict__ fcW,
                                              const float* __restrict__ fcb,
                                              const float* __restrict__ f1W,
                                              const float* __restrict__ f1b,
                                              float* __restrict__ out) {
    __shared__ float zrow[512];
    __shared__ float hid[256];
    __shared__ float o[16];
    int b = blockIdx.x, t = threadIdx.x;
    zrow[t]       = x1[b * HH + t]       + x2[b * HH + t];
    zrow[t + 256] = x1[b * HH + t + 256] + x2[b * HH + t + 256];
    __syncthreads();
    float acc = fcb[t];
    for (int k = 0; k < 512; ++k) acc += zrow[k] * fcW[k * 256 + t];
    hid[t] = fmaxf(acc, 0.f);
    __syncthreads();
    if (t < OUTC) {
        float a = f1b[t];
        for (int k = 0; k < 256; ++k) a += hid[k] * f1W[k * OUTC + t];
        o[t] = a;
    }
    __syncthreads();
    if (t == 0) {
        float mx = -1e30f;
        for (int j = 0; j < OUTC; ++j) mx = fmaxf(mx, o[j]);
        float s = 0.f;
        for (int j = 0; j < OUTC; ++j) s += expf(o[j] - mx);
        float lse = mx + logf(s);
        for (int j = 0; j < OUTC; ++j) out[b * OUTC + j] = o[j] - lse;
    }
}

// ---------------- launch ----------------
extern "C" void kernel_launch(void* const* d_in, const int* in_sizes, int n_in,
                              void* d_out, int out_size, void* d_ws, size_t ws_size,
                              hipStream_t stream) {
    const float* x      = (const float*)d_in[0];
    const int*   eidx   = (const int*)  d_in[1];
    const int*   batch  = (const int*)  d_in[2];
    const float* W1     = (const float*)d_in[3];
    const float* a_src1 = (const float*)d_in[4];
    const float* a_dst1 = (const float*)d_in[5];
    const float* b1     = (const float*)d_in[6];
    const float* g1     = (const float*)d_in[7];
    const float* be1    = (const float*)d_in[8];
    const float* W2     = (const float*)d_in[9];
    const float* a_src2 = (const float*)d_in[10];
    const float* a_dst2 = (const float*)d_in[11];
    const float* b2     = (const float*)d_in[12];
    const float* g2     = (const float*)d_in[13];
    const float* be2    = (const float*)d_in[14];
    const float* fcW    = (const float*)d_in[15];
    const float* fcb    = (const float*)d_in[16];
    const float* fc1W   = (const float*)d_in[17];
    const float* fc1b   = (const float*)d_in[18];
    float* out = (float*)d_out;

    // workspace carve-up (all offsets 16B-aligned)
    float*          bufB  = (float*)d_ws;                         // N*H f32
    unsigned short* h16   = (unsigned short*)(bufB + (size_t)NN * HH);   // N*H bf16
    unsigned short* b16   = h16 + (size_t)NN * HH;                // N*H bf16 (also x16)
    unsigned short* x16   = b16;                                  // overlap: x16 dead before b16 written
    unsigned short* w1t   = b16 + (size_t)NN * HH;                // 512*128
    unsigned short* w2t   = w1t + 512 * FIN;                      // 512*512
    float* es     = (float*)(w2t + 512 * HH);                     // N
    float* ed     = es + NN;                                      // N
    float* bnsum1 = ed + NN;                                      // H
    float* bnsq1  = bnsum1 + HH;
    float* bnsum2 = bnsq1 + HH;
    float* bnsq2  = bnsum2 + HH;
    float* x1     = bnsq2 + HH;                                   // B*H
    float* x2     = x1 + BB * HH;                                 // B*H
    int*   deg    = (int*)(x2 + BB * HH);                         // N
    int*   offs   = deg + NN;                                     // N+1
    int*   cursor = offs + NN + 1;                                // N
    int*   csr    = cursor + NN;                                  // ETOT

    hipMemsetAsync(bnsum1, 0, 4 * HH * sizeof(float), stream);
    hipMemsetAsync(deg, 0, NN * sizeof(int), stream);
    hipMemsetAsync(cursor, 0, NN * sizeof(int), stream);

    // CSR build (shared by both layers)
    int eblocks = (ETOT + 255) / 256;
    k_deg<<<eblocks, 256, 0, stream>>>(eidx, deg);
    k_scan<<<1, 1024, 0, stream>>>(deg, offs);
    k_fill<<<eblocks, 256, 0, stream>>>(eidx, offs, cursor, csr);

    // bf16 precasts
    k_cast<<<(NN * FIN / 4 + 255) / 256, 256, 0, stream>>>(x, x16, NN * FIN / 4);
    k_wt<FIN><<<(512 * FIN + 255) / 256, 256, 0, stream>>>(W1, w1t);
    k_wt<HH> <<<(512 * HH + 255) / 256, 256, 0, stream>>>(W2, w2t);

    dim3 gemmGrid(HH / 128, (NN + 127) / 128);

    // ---- layer 1 ----
    k_gemm16<FIN><<<gemmGrid, 256, 0, stream>>>(x16, w1t, h16, NN);
    k_scores16<<<(NN + 3) / 4, 256, 0, stream>>>(h16, a_src1, a_dst1, es, ed);
    k_agg<<<NN, 256, 0, stream>>>(h16, es, ed, offs, csr, b1, bufB);
    k_bnstats<<<400, 256, 0, stream>>>(bufB, bnsum1, bnsq1);
    k_bnapply<<<2048, 256, 0, stream>>>(bufB, b16, bnsum1, bnsq1, g1, be1);
    k_pool<<<BB, 256, 0, stream>>>(bufB, batch, x1);

    // ---- layer 2 ----
    k_gemm16<HH><<<gemmGrid, 256, 0, stream>>>(b16, w2t, h16, NN);
    k_scores16<<<(NN + 3) / 4, 256, 0, stream>>>(h16, a_src2, a_dst2, es, ed);
    k_agg<<<NN, 256, 0, stream>>>(h16, es, ed, offs, csr, b2, bufB);
    k_bnstats<<<400, 256, 0, stream>>>(bufB, bnsum2, bnsq2);
    k_bnapply<<<2048, 256, 0, stream>>>(bufB, h16, bnsum2, bnsq2, g2, be2);  // bf16 out unused
    k_pool<<<BB, 256, 0, stream>>>(bufB, batch, x2);

    // ---- head ----
    k_head<<<BB, 256, 0, stream>>>(x1, x2, fcW, fcb, fc1W, fc1b, out);
}

// Round 3
// 377.203 us; speedup vs baseline: 2.3398x; 1.3883x over previous
//
#include <hip/hip_runtime.h>
#include <hip/hip_bf16.h>
#include <math.h>

#define NN 20000
#define EE 320000
#define ETOT (EE + NN)   // 340000
#define BB 64
#define FIN 128
#define HH 512
#define OUTC 10
#define POOL_CH 16

typedef __attribute__((ext_vector_type(8))) short short8;
typedef __attribute__((ext_vector_type(4))) float f32x4;

__device__ __forceinline__ unsigned short f2bf(float f) {
    unsigned int u = __float_as_uint(f);
    u += 0x7FFFu + ((u >> 16) & 1u);
    return (unsigned short)(u >> 16);
}
__device__ __forceinline__ float bf2f_lo(unsigned int u) { return __uint_as_float(u << 16); }
__device__ __forceinline__ float bf2f_hi(unsigned int u) { return __uint_as_float(u & 0xFFFF0000u); }

// ---------------- cast x -> bf16 ----------------
__global__ __launch_bounds__(256) void k_cast(const float* __restrict__ x,
                                              unsigned short* __restrict__ x16, int n4) {
    int i = blockIdx.x * 256 + threadIdx.x;
    if (i >= n4) return;
    float4 v = ((const float4*)x)[i];
    unsigned short o[4] = { f2bf(v.x), f2bf(v.y), f2bf(v.z), f2bf(v.w) };
    *(ushort4*)(x16 + 4 * (size_t)i) = *(const ushort4*)o;
}

// ---------------- W [K][512] f32 -> WT [512][K] bf16 ----------------
template<int K>
__global__ __launch_bounds__(256) void k_wt(const float* __restrict__ W,
                                            unsigned short* __restrict__ WT) {
    int idx = blockIdx.x * 256 + threadIdx.x;
    if (idx >= 512 * K) return;
    int n = idx / K, k = idx % K;
    WT[idx] = f2bf(W[k * 512 + n]);
}

// ---------------- bf16 MFMA GEMM: C16[M,512] = A16[M,K] @ (BT16[512,K])^T ----
template<int K>
__global__ __launch_bounds__(256) void k_gemm16(const unsigned short* __restrict__ A,
                                                const unsigned short* __restrict__ BT,
                                                unsigned short* __restrict__ C,
                                                int M) {
    __shared__ __align__(16) short As[128][72];   // +8 pad: 144B row stride -> conflict-free frags
    __shared__ __align__(16) short Bs[128][72];
    const int tid  = threadIdx.x;
    const int lane = tid & 63;
    const int wid  = tid >> 6;
    const int wr = wid >> 1, wc = wid & 1;        // 2x2 wave grid, 64x64 per wave
    const int row0 = blockIdx.y * 128, col0 = blockIdx.x * 128;
    f32x4 acc[4][4] = {};
    for (int k0 = 0; k0 < K; k0 += 64) {
        #pragma unroll
        for (int i = 0; i < 4; ++i) {
            int cid = tid + i * 256;              // 1024 chunks of 8 bf16
            int r = cid >> 3, c = cid & 7;
            int ga = min(row0 + r, M - 1);
            uint4 av = *(const uint4*)(A  + (size_t)ga * K + k0 + c * 8);
            *(uint4*)&As[r][c * 8] = av;
            uint4 bv = *(const uint4*)(BT + (size_t)(col0 + r) * K + k0 + c * 8);
            *(uint4*)&Bs[r][c * 8] = bv;
        }
        __syncthreads();
        #pragma unroll
        for (int kk = 0; kk < 64; kk += 32) {
            short8 af[4], bf[4];
            const int koff = kk + (lane >> 4) * 8;
            const int ar = wr * 64 + (lane & 15);
            const int br = wc * 64 + (lane & 15);
            #pragma unroll
            for (int m = 0; m < 4; ++m) af[m] = *(const short8*)&As[ar + m * 16][koff];
            #pragma unroll
            for (int n = 0; n < 4; ++n) bf[n] = *(const short8*)&Bs[br + n * 16][koff];
            #pragma unroll
            for (int m = 0; m < 4; ++m)
                #pragma unroll
                for (int n = 0; n < 4; ++n)
                    acc[m][n] = __builtin_amdgcn_mfma_f32_16x16x32_bf16(af[m], bf[n], acc[m][n], 0, 0, 0);
        }
        __syncthreads();
    }
    const int crow = (lane >> 4) * 4;
    const int ccol = lane & 15;
    #pragma unroll
    for (int m = 0; m < 4; ++m) {
        #pragma unroll
        for (int j = 0; j < 4; ++j) {
            int gr = row0 + wr * 64 + m * 16 + crow + j;
            if (gr < M) {
                #pragma unroll
                for (int n = 0; n < 4; ++n)
                    C[(size_t)gr * 512 + col0 + wc * 64 + n * 16 + ccol] = f2bf(acc[m][n][j]);
            }
        }
    }
}

// ---------------- attention scores from bf16 h: one wave per row ----------------
__global__ __launch_bounds__(256) void k_scores16(const unsigned short* __restrict__ h16,
                                                  const float* __restrict__ a_s,
                                                  const float* __restrict__ a_d,
                                                  float* __restrict__ es,
                                                  float* __restrict__ ed) {
    int wid  = threadIdx.x >> 6;
    int lane = threadIdx.x & 63;
    int row  = blockIdx.x * 4 + wid;
    if (row >= NN) return;
    uint4 hv = *(const uint4*)(h16 + (size_t)row * 512 + lane * 8);
    const float4* as4 = (const float4*)a_s;
    const float4* ad4 = (const float4*)a_d;
    float4 a0 = as4[2 * lane], a1 = as4[2 * lane + 1];
    float4 d0 = ad4[2 * lane], d1 = ad4[2 * lane + 1];
    float h0 = bf2f_lo(hv.x), h1 = bf2f_hi(hv.x), h2 = bf2f_lo(hv.y), h3 = bf2f_hi(hv.y);
    float h4 = bf2f_lo(hv.z), h5 = bf2f_hi(hv.z), h6 = bf2f_lo(hv.w), h7 = bf2f_hi(hv.w);
    float s = h0*a0.x + h1*a0.y + h2*a0.z + h3*a0.w + h4*a1.x + h5*a1.y + h6*a1.z + h7*a1.w;
    float d = h0*d0.x + h1*d0.y + h2*d0.z + h3*d0.w + h4*d1.x + h5*d1.y + h6*d1.z + h7*d1.w;
    #pragma unroll
    for (int o = 32; o > 0; o >>= 1) {
        s += __shfl_down(s, o);
        d += __shfl_down(d, o);
    }
    if (lane == 0) { es[row] = s; ed[row] = d; }
}

// ---------------- CSR build ----------------
__global__ void k_deg(const int* __restrict__ eidx, int* __restrict__ deg) {
    int e = blockIdx.x * 256 + threadIdx.x;
    if (e >= ETOT) return;
    int d = (e < EE) ? eidx[EE + e] : (e - EE);
    atomicAdd(&deg[d], 1);
}

__global__ __launch_bounds__(1024) void k_scan(const int* __restrict__ deg,
                                               int* __restrict__ offs) {
    __shared__ int partials[1024];
    int t = threadIdx.x;
    const int per = (NN + 1023) / 1024;   // 20
    int b0 = t * per;
    int s = 0;
    for (int i = 0; i < per; ++i) { int idx = b0 + i; if (idx < NN) s += deg[idx]; }
    partials[t] = s;
    __syncthreads();
    for (int off = 1; off < 1024; off <<= 1) {
        int v = (t >= off) ? partials[t - off] : 0;
        __syncthreads();
        partials[t] += v;
        __syncthreads();
    }
    int base = (t == 0) ? 0 : partials[t - 1];
    for (int i = 0; i < per; ++i) {
        int idx = b0 + i;
        if (idx < NN) { offs[idx] = base; base += deg[idx]; }
    }
    if (t == 1023) offs[NN] = partials[1023];
}

__global__ void k_fill(const int* __restrict__ eidx, const int* __restrict__ offs,
                       int* __restrict__ cursor, int* __restrict__ csr) {
    int e = blockIdx.x * 256 + threadIdx.x;
    if (e >= ETOT) return;
    int s, d;
    if (e < EE) { s = eidx[e]; d = eidx[EE + e]; }
    else        { s = e - EE;  d = e - EE; }
    int pos = offs[d] + atomicAdd(&cursor[d], 1);
    csr[pos] = s;
}

// ---------------- per-dst softmax-weighted aggregation (bf16 gathers) ----------------
__global__ __launch_bounds__(256) void k_agg(const unsigned short* __restrict__ h16,
                                             const float* __restrict__ es,
                                             const float* __restrict__ ed,
                                             const int* __restrict__ offs,
                                             const int* __restrict__ csr,
                                             const float* __restrict__ bias,
                                             float* __restrict__ out) {
    __shared__ float red[4];
    __shared__ float bcast;
    __shared__ float sh_w[256];
    __shared__ int   sh_s[256];
    int dnode = blockIdx.x;
    int beg = offs[dnode], end = offs[dnode + 1];
    float edv = ed[dnode];
    int tid = threadIdx.x;
    int lane = tid & 63, w4 = tid >> 6;

    // pass 1: z = sum exp(leaky_relu(es+ed))   (no max shift: |e| <~ 10 << 88)
    float lz = 0.f;
    for (int i = beg + tid; i < end; i += 256) {
        float v = es[csr[i]] + edv;
        v = v > 0.f ? v : 0.2f * v;
        lz += __expf(v);
    }
    #pragma unroll
    for (int o = 32; o > 0; o >>= 1) lz += __shfl_down(lz, o);
    if (lane == 0) red[w4] = lz;
    __syncthreads();
    if (tid == 0) bcast = red[0] + red[1] + red[2] + red[3];
    __syncthreads();
    float inv = 1.f / (bcast + 1e-16f);

    // pass 2: chunked: per-edge weight computed once into LDS, then coalesced row gathers
    float a0 = 0.f, a1 = 0.f;
    const int f = tid * 2;
    for (int c0 = beg; c0 < end; c0 += 256) {
        int nc = min(256, end - c0);
        __syncthreads();
        if (tid < nc) {
            int s = csr[c0 + tid];
            float v = es[s] + edv;
            v = v > 0.f ? v : 0.2f * v;
            sh_w[tid] = __expf(v) * inv;
            sh_s[tid] = s;
        }
        __syncthreads();
        for (int j = 0; j < nc; ++j) {
            int s = sh_s[j];
            float w = sh_w[j];
            unsigned int u = *(const unsigned int*)(h16 + (size_t)s * 512 + f);
            a0 += w * bf2f_lo(u);
            a1 += w * bf2f_hi(u);
        }
    }
    out[(size_t)dnode * 512 + f]     = a0 + bias[f];
    out[(size_t)dnode * 512 + f + 1] = a1 + bias[f + 1];
}

// ---------------- BatchNorm stats / apply ----------------
__global__ __launch_bounds__(256) void k_bnstats(const float* __restrict__ X,
                                                 float* __restrict__ sum,
                                                 float* __restrict__ sumsq) {
    int f0 = threadIdx.x, f1 = threadIdx.x + 256;
    int rows_per = (NN + gridDim.x - 1) / gridDim.x;
    int r0 = blockIdx.x * rows_per;
    int r1 = min(NN, r0 + rows_per);
    float s0 = 0, s1 = 0, q0 = 0, q1 = 0;
    for (int r = r0; r < r1; ++r) {
        float v0 = X[(size_t)r * HH + f0];
        float v1 = X[(size_t)r * HH + f1];
        s0 += v0; q0 += v0 * v0;
        s1 += v1; q1 += v1 * v1;
    }
    atomicAdd(&sum[f0], s0);   atomicAdd(&sum[f1], s1);
    atomicAdd(&sumsq[f0], q0); atomicAdd(&sumsq[f1], q1);
}

// BN + ReLU, writes f32 (for pool) and bf16 (for next GEMM)
__global__ void k_bnapply(float* __restrict__ X, unsigned short* __restrict__ X16,
                          const float* __restrict__ sum, const float* __restrict__ sumsq,
                          const float* __restrict__ g, const float* __restrict__ be) {
    const float invN = 1.f / (float)NN;
    size_t stride = (size_t)gridDim.x * 256;
    for (size_t i = (size_t)blockIdx.x * 256 + threadIdx.x; i < (size_t)NN * HH; i += stride) {
        int f = (int)(i & (HH - 1));
        float mu = sum[f] * invN;
        float var = sumsq[f] * invN - mu * mu;
        float v = (X[i] - mu) * rsqrtf(var + 1e-5f) * g[f] + be[f];
        v = v > 0.f ? v : 0.f;
        X[i] = v;
        X16[i] = f2bf(v);
    }
}

// ---------------- mean pool per graph: (graph, chunk) 2-D grid + atomics ----------------
__device__ __forceinline__ int lb_search(const int* __restrict__ batch, int val) {
    int lo = 0, hi = NN;
    while (lo < hi) { int mid = (lo + hi) >> 1; if (batch[mid] < val) lo = mid + 1; else hi = mid; }
    return lo;
}

__global__ __launch_bounds__(256) void k_pool(const float* __restrict__ X,
                                              const int* __restrict__ batch,
                                              float* __restrict__ P) {
    int b = blockIdx.x;
    int ch = blockIdx.y;
    int lo = lb_search(batch, b), hi = lb_search(batch, b + 1);
    int len = hi - lo;
    float inv = 1.f / fmaxf((float)len, 1.f);
    int per = (len + POOL_CH - 1) / POOL_CH;
    int r0 = lo + ch * per;
    int r1 = min(hi, r0 + per);
    if (r0 >= r1) return;
    int f0 = threadIdx.x, f1 = threadIdx.x + 256;
    float s0 = 0.f, s1 = 0.f;
    for (int r = r0; r < r1; ++r) {
        s0 += X[(size_t)r * HH + f0];
        s1 += X[(size_t)r * HH + f1];
    }
    atomicAdd(&P[b * HH + f0], s0 * inv);
    atomicAdd(&P[b * HH + f1], s1 * inv);
}

// ---------------- final FC head + log_softmax ----------------
__global__ __launch_bounds__(256) void k_head(const float* __restrict__ x1,
                                              const float* __restrict__ x2,
                                              const float* __restrict__ fcW,
                                              const float* __restrict__ fcb,
                                              const float* __restrict__ f1W,
                                              const float* __restrict__ f1b,
                                              float* __restrict__ out) {
    __shared__ float zrow[512];
    __shared__ float hid[256];
    __shared__ float o[16];
    int b = blockIdx.x, t = threadIdx.x;
    zrow[t]       = x1[b * HH + t]       + x2[b * HH + t];
    zrow[t + 256] = x1[b * HH + t + 256] + x2[b * HH + t + 256];
    __syncthreads();
    float acc = fcb[t];
    for (int k = 0; k < 512; ++k) acc += zrow[k] * fcW[k * 256 + t];
    hid[t] = fmaxf(acc, 0.f);
    __syncthreads();
    if (t < OUTC) {
        float a = f1b[t];
        for (int k = 0; k < 256; ++k) a += hid[k] * f1W[k * OUTC + t];
        o[t] = a;
    }
    __syncthreads();
    if (t == 0) {
        float mx = -1e30f;
        for (int j = 0; j < OUTC; ++j) mx = fmaxf(mx, o[j]);
        float s = 0.f;
        for (int j = 0; j < OUTC; ++j) s += expf(o[j] - mx);
        float lse = mx + logf(s);
        for (int j = 0; j < OUTC; ++j) out[b * OUTC + j] = o[j] - lse;
    }
}

// ---------------- launch ----------------
extern "C" void kernel_launch(void* const* d_in, const int* in_sizes, int n_in,
                              void* d_out, int out_size, void* d_ws, size_t ws_size,
                              hipStream_t stream) {
    const float* x      = (const float*)d_in[0];
    const int*   eidx   = (const int*)  d_in[1];
    const int*   batch  = (const int*)  d_in[2];
    const float* W1     = (const float*)d_in[3];
    const float* a_src1 = (const float*)d_in[4];
    const float* a_dst1 = (const float*)d_in[5];
    const float* b1     = (const float*)d_in[6];
    const float* g1     = (const float*)d_in[7];
    const float* be1    = (const float*)d_in[8];
    const float* W2     = (const float*)d_in[9];
    const float* a_src2 = (const float*)d_in[10];
    const float* a_dst2 = (const float*)d_in[11];
    const float* b2     = (const float*)d_in[12];
    const float* g2     = (const float*)d_in[13];
    const float* be2    = (const float*)d_in[14];
    const float* fcW    = (const float*)d_in[15];
    const float* fcb    = (const float*)d_in[16];
    const float* fc1W   = (const float*)d_in[17];
    const float* fc1b   = (const float*)d_in[18];
    float* out = (float*)d_out;

    // workspace carve-up (all offsets 16B-aligned)
    float*          bufB  = (float*)d_ws;                         // N*H f32
    unsigned short* h16   = (unsigned short*)(bufB + (size_t)NN * HH);   // N*H bf16
    unsigned short* b16   = h16 + (size_t)NN * HH;                // N*H bf16 (also x16)
    unsigned short* x16   = b16;                                  // overlap: x16 dead before b16 written
    unsigned short* w1t   = b16 + (size_t)NN * HH;                // 512*128
    unsigned short* w2t   = w1t + 512 * FIN;                      // 512*512
    float* es     = (float*)(w2t + 512 * HH);                     // N
    float* ed     = es + NN;                                      // N
    float* bnsum1 = ed + NN;                                      // H
    float* bnsq1  = bnsum1 + HH;
    float* bnsum2 = bnsq1 + HH;
    float* bnsq2  = bnsum2 + HH;
    float* x1     = bnsq2 + HH;                                   // B*H
    float* x2     = x1 + BB * HH;                                 // B*H
    int*   deg    = (int*)(x2 + BB * HH);                         // N
    int*   offs   = deg + NN;                                     // N+1
    int*   cursor = offs + NN + 1;                                // N
    int*   csr    = cursor + NN;                                  // ETOT

    hipMemsetAsync(bnsum1, 0, 4 * HH * sizeof(float), stream);
    hipMemsetAsync(x1, 0, 2 * BB * HH * sizeof(float), stream);   // x1 + x2
    hipMemsetAsync(deg, 0, NN * sizeof(int), stream);
    hipMemsetAsync(cursor, 0, NN * sizeof(int), stream);

    // CSR build (shared by both layers)
    int eblocks = (ETOT + 255) / 256;
    k_deg<<<eblocks, 256, 0, stream>>>(eidx, deg);
    k_scan<<<1, 1024, 0, stream>>>(deg, offs);
    k_fill<<<eblocks, 256, 0, stream>>>(eidx, offs, cursor, csr);

    // bf16 precasts
    k_cast<<<(NN * FIN / 4 + 255) / 256, 256, 0, stream>>>(x, x16, NN * FIN / 4);
    k_wt<FIN><<<(512 * FIN + 255) / 256, 256, 0, stream>>>(W1, w1t);
    k_wt<HH> <<<(512 * HH + 255) / 256, 256, 0, stream>>>(W2, w2t);

    dim3 gemmGrid(HH / 128, (NN + 127) / 128);
    dim3 poolGrid(BB, POOL_CH);

    // ---- layer 1 ----
    k_gemm16<FIN><<<gemmGrid, 256, 0, stream>>>(x16, w1t, h16, NN);
    k_scores16<<<(NN + 3) / 4, 256, 0, stream>>>(h16, a_src1, a_dst1, es, ed);
    k_agg<<<NN, 256, 0, stream>>>(h16, es, ed, offs, csr, b1, bufB);
    k_bnstats<<<400, 256, 0, stream>>>(bufB, bnsum1, bnsq1);
    k_bnapply<<<2048, 256, 0, stream>>>(bufB, b16, bnsum1, bnsq1, g1, be1);
    k_pool<<<poolGrid, 256, 0, stream>>>(bufB, batch, x1);

    // ---- layer 2 ----
    k_gemm16<HH><<<gemmGrid, 256, 0, stream>>>(b16, w2t, h16, NN);
    k_scores16<<<(NN + 3) / 4, 256, 0, stream>>>(h16, a_src2, a_dst2, es, ed);
    k_agg<<<NN, 256, 0, stream>>>(h16, es, ed, offs, csr, b2, bufB);
    k_bnstats<<<400, 256, 0, stream>>>(bufB, bnsum2, bnsq2);
    k_bnapply<<<2048, 256, 0, stream>>>(bufB, h16, bnsum2, bnsq2, g2, be2);  // bf16 out unused
    k_pool<<<poolGrid, 256, 0, stream>>>(bufB, batch, x2);

    // ---- head ----
    k_head<<<BB, 256, 0, stream>>>(x1, x2, fcW, fcb, fc1W, fc1b, out);
}